// Round 10
// baseline (239.846 us; speedup 1.0000x reference)
//
#include <hip/hip_runtime.h>
#include <math.h>

#define S0 3600
#define S1 720
#define S2 144
#define S3 36
#define S4 9
#define NEGF (-1e30f)

// ---- workspace layout (bytes). ws is 256 MiB (harness fill = 262144 KB).
static constexpr size_t OFF_X0  = 0;                                    // f32 [3600*3600] = 51,840,000
static constexpr size_t OFF_M0B = (size_t)S0 * S0 * 4;                  // u32 bitfield    = 1,620,000
static constexpr size_t OFF_H1  = OFF_M0B + 1620000;                    // f32 [32]
static constexpr size_t OFF_CNT = OFF_H1 + 128;                         // u32 completion counter
static constexpr size_t OFF_Y1H = OFF_CNT + 32;                         // bf16 [720*720*16] = 16,588,800
static constexpr size_t OFF_M1  = OFF_Y1H + (size_t)S1 * S1 * 16 * 2;   // u8  [720*720]
// aliased into dead x0 region (written only AFTER k_l1 part completes):
static constexpr size_t OFF_M2  = 1330000;                              // u8  [144*144]
static constexpr size_t OFF_Y3  = OFF_M2 + 20736;                       // f32 [36*36*128]
static constexpr size_t OFF_M3  = OFF_Y3 + (size_t)S3 * S3 * 128 * 4;   // u8  [36*36]
static constexpr size_t OFF_Y4  = OFF_M3 + 1296;                        // f32 [9*9*256]
// high region (beyond 80 MB): no aliasing with x0 -> converter can run with k_l1
static constexpr size_t OFF_Y2H = 80000000;                             // bf16 [20736*64] = 2,654,208
static constexpr size_t OFF_W2H = 84000000;                             // bf16 frags = 53,248
static constexpr size_t OFF_W3H = 84200000;                             // bf16 frags = 409,600
static constexpr size_t OFF_W4H = 84700000;                             // bf16 frags = 1,638,400 (ends 86.3 MB)

typedef __attribute__((ext_vector_type(8))) short bf16x8;
typedef __attribute__((ext_vector_type(4))) float f32x4;

__device__ __forceinline__ float eluf(float x) { return x > 0.f ? x : expm1f(x); }
__device__ __forceinline__ unsigned short f2bf(float f) {
    unsigned u = __float_as_uint(f);
    unsigned r = u + 0x7FFFu + ((u >> 16) & 1u);
    return (unsigned short)(r >> 16);
}
__device__ __forceinline__ float bf2f(unsigned short h) {
    return __uint_as_float((unsigned)h << 16);
}

// ---- zero x0 at the active coordinates --------------------------------------
__global__ __launch_bounds__(256) void k_zero(const int* __restrict__ coords,
                                              float* __restrict__ x0, int P) {
    int i = blockIdx.x * 256 + threadIdx.x;
    if (i >= P) return;
    x0[coords[2 * i] * S0 + coords[2 * i + 1]] = 0.f;
}

// ---- scatter points onto dense grid -----------------------------------------
__global__ __launch_bounds__(256) void k_scatter(const int* __restrict__ coords,
                                                 const float* __restrict__ feats,
                                                 float* __restrict__ x0,
                                                 unsigned* __restrict__ m0b, int P) {
    int i = blockIdx.x * 256 + threadIdx.x;
    if (i >= P) return;
    int r = coords[2 * i], c = coords[2 * i + 1];
    int idx = r * S0 + c;
    atomicAdd(&x0[idx], feats[i]);
    atomicOr(&m0b[idx >> 5], 1u << (idx & 31));
}

// ---- layer 1 (blocks 0..2024) + weight converter (blocks 2025..2537) --------
// l1: sparse conv 5x5 1->10 + ELU + maxpool5, bf16 output padded to 16 ch.
// Inactive sites write ONLY m1=0 (y1h left stale; k_l2 stages zeros via m1).
// cvtw: w2/w3/w4 -> MFMA B-fragment bf16 (independent; overlaps l1).
__global__ __launch_bounds__(256) void k_l1c(const float* __restrict__ x0,
                                             const unsigned* __restrict__ m0b,
                                             const float* __restrict__ w1,
                                             const float* __restrict__ w2,
                                             const float* __restrict__ w3,
                                             const float* __restrict__ w4,
                                             unsigned short* __restrict__ y1h,
                                             unsigned char* __restrict__ m1,
                                             unsigned short* __restrict__ w2h,
                                             unsigned short* __restrict__ w3h,
                                             unsigned short* __restrict__ w4h) {
    int b = blockIdx.x;
    int tid = threadIdx.x;
    if (b >= 2025) {                     // ---- converter branch ----
        int blk = b - 2025;
        if (blk < 13) {
            int t = blk * 256 + tid;
            int s = t >> 8, rem = t & 255;
            int nt = rem >> 6, lane = rem & 63;
            int quad = lane >> 4, n = lane & 15;
            int tap = 2 * s + (quad >> 1);
#pragma unroll
            for (int j = 0; j < 8; j++) {
                int ci = (quad & 1) * 8 + j;
                float v = 0.f;
                if (tap < 25 && ci < 10) v = w2[(tap * 10 + ci) * 64 + nt * 16 + n];
                w2h[(size_t)t * 8 + j] = f2bf(v);
            }
        } else if (blk < 113) {
            int t = (blk - 13) * 256 + tid;
            int s = t >> 9, rem = t & 511;
            int nt = rem >> 6, lane = rem & 63;
            int quad = lane >> 4, n = lane & 15;
            int t5 = s >> 1, cib = s & 1;
#pragma unroll
            for (int j = 0; j < 8; j++) {
                int ci = cib * 32 + quad * 8 + j;
                float v = w3[(size_t)(t5 * 64 + ci) * 128 + nt * 16 + n];
                w3h[(size_t)t * 8 + j] = f2bf(v);
            }
        } else {
            int t = (blk - 113) * 256 + tid;
            int s = t >> 10, rem = t & 1023;
            int nt = rem >> 6, lane = rem & 63;
            int quad = lane >> 4, n = lane & 15;
            int t5 = s >> 2, cib = s & 3;
#pragma unroll
            for (int j = 0; j < 8; j++) {
                int ci = cib * 32 + quad * 8 + j;
                float v = w4[(size_t)(t5 * 128 + ci) * 256 + nt * 16 + n];
                w4h[(size_t)t * 8 + j] = f2bf(v);
            }
        }
        return;
    }
    // ---- l1 branch ----
    __shared__ float w1s[250];
    if (tid < 250) w1s[tid] = w1[tid];
    __syncthreads();
    int t = b * 256 + tid;                // 0..720*720-1
    int pr = t / S1, pc = t % S1;
    int r0 = pr * 5 - 2, c0 = pc * 5 - 2;
    unsigned rows[9];
#pragma unroll
    for (int rr = 0; rr < 9; rr++) {
        unsigned bits = 0;
        int gr = r0 + rr;
        if (gr >= 0 && gr < S0) {
            int cs = c0 < 0 ? 0 : c0;
            int ce = c0 + 8 > S0 - 1 ? S0 - 1 : c0 + 8;
            int span = ce - cs;
            size_t i0 = (size_t)gr * S0 + cs;
            unsigned sh = (unsigned)(i0 & 31);
            unsigned long long two = (unsigned long long)m0b[i0 >> 5] >> sh;
            if ((int)sh + span >= 32)
                two |= (unsigned long long)m0b[(i0 >> 5) + 1] << (32 - sh);
            bits = (unsigned)(two & ((1u << (span + 1)) - 1));
            bits <<= (cs - c0);
        }
        rows[rr] = bits;
    }
    unsigned any25 = 0;
#pragma unroll
    for (int dy = 0; dy < 5; dy++) any25 |= (rows[2 + dy] >> 2) & 0x1Fu;
    if (!any25) {
        m1[t] = 0;
        return;
    }
    float2 mx[5];
#pragma unroll
    for (int q = 0; q < 5; q++) mx[q] = make_float2(NEGF, NEGF);
    for (int dy = 0; dy < 5; dy++) {
        unsigned crow = (rows[2 + dy] >> 2) & 0x1Fu;
        while (crow) {
            int dx = __ffs(crow) - 1; crow &= crow - 1;
            float2 acc[5];
#pragma unroll
            for (int q = 0; q < 5; q++) acc[q] = make_float2(0.f, 0.f);
#pragma unroll
            for (int ky = 0; ky < 5; ky++) {
                unsigned nrow = (rows[dy + ky] >> dx) & 0x1Fu;
                size_t rowbase = (size_t)(r0 + dy + ky) * S0 + (c0 + dx);
                while (nrow) {
                    int kx = __ffs(nrow) - 1; nrow &= nrow - 1;
                    float xv = x0[rowbase + kx];
                    const float2* wp = (const float2*)&w1s[(ky * 5 + kx) * 10];
#pragma unroll
                    for (int q = 0; q < 5; q++) {
                        float2 w = wp[q];
                        acc[q].x = fmaf(xv, w.x, acc[q].x);
                        acc[q].y = fmaf(xv, w.y, acc[q].y);
                    }
                }
            }
#pragma unroll
            for (int q = 0; q < 5; q++) {
                mx[q].x = fmaxf(mx[q].x, acc[q].x);
                mx[q].y = fmaxf(mx[q].y, acc[q].y);
            }
        }
    }
    unsigned u[8];
#pragma unroll
    for (int q = 0; q < 5; q++) {
        unsigned short h0 = f2bf(eluf(mx[q].x));
        unsigned short h1 = f2bf(eluf(mx[q].y));
        u[q] = (unsigned)h0 | ((unsigned)h1 << 16);
    }
    u[5] = 0; u[6] = 0; u[7] = 0;
    uint4* yo = (uint4*)&y1h[(size_t)t * 16];
    yo[0] = make_uint4(u[0], u[1], u[2], u[3]);
    yo[1] = make_uint4(u[4], u[5], u[6], u[7]);
    m1[t] = 1;
}

// ---- layer 2: MFMA conv 5x5 10->64 + ELU + maxpool5 -> 144^2 ----------------
// Block = 2x4 pool sites (2592 blocks); halo 14x24, 48 B/cell LDS stride.
// Wave (a = site-row, bq = nt-pair) computes 4 sites x 2 mt x 2 ntl.
// Staging gated on m1 (inactive cells stage zeros; y1h not read there).
__global__ __launch_bounds__(256, 2) void k_l2(const unsigned short* __restrict__ y1h,
                                               const unsigned char* __restrict__ m1,
                                               const unsigned short* __restrict__ w2h,
                                               unsigned short* __restrict__ y2h,
                                               unsigned char* __restrict__ m2) {
    __shared__ unsigned short winh[408 * 24];   // 19.6 KB (408: padded-tap reads ok)
    __shared__ unsigned char sm[336];
    int b = blockIdx.x;                  // 0..2591
    int bpr = b / 36, bpc = b % 36;
    int r0 = bpr * 10 - 2, c0 = bpc * 20 - 2;
    int tid = threadIdx.x;
    for (int k = tid; k < 336; k += 256) {
        int hr = k / 24, hc = k % 24;
        int gr = r0 + hr, gc = c0 + hc;
        bool ok = (gr >= 0 && gr < S1 && gc >= 0 && gc < S1);
        unsigned char msk = ok ? m1[gr * S1 + gc] : (unsigned char)0;
        sm[k] = msk;
        uint4 v0 = make_uint4(0, 0, 0, 0), v1 = v0;
        if (msk) {
            const uint4* src = (const uint4*)&y1h[(size_t)(gr * S1 + gc) * 16];
            v0 = src[0];
            v1 = src[1];
        }
        uint4* dh = (uint4*)&winh[k * 24];
        dh[0] = v0;
        dh[1] = v1;
    }
    __syncthreads();
    int wv = tid >> 6;
    int a = wv >> 1, bq = wv & 1;        // a = site row (0..1), bq = nt-pair
    int lane = tid & 63, quad = lane >> 4, n = lane & 15;
    // mbits via ballot: 2 ballots cover 4 site-cols
    int cql = lane & 31, scl = lane >> 5;
    unsigned mb[4];
#pragma unroll
    for (int g = 0; g < 2; g++) {
        bool pv = false;
        int sc = g * 2 + scl;
        if (cql < 25)
            pv = sm[(a * 5 + 2 + cql / 5) * 24 + sc * 5 + 2 + cql % 5] != 0;
        unsigned long long bal = __ballot(pv);
        mb[g * 2] = (unsigned)(bal & 0x1FFFFFFull);
        mb[g * 2 + 1] = (unsigned)((bal >> 32) & 0x1FFFFFFull);
    }
    const bf16x8* wh8 = (const bf16x8*)w2h;
    const bf16x8* xh8 = (const bf16x8*)winh;
    int oct = quad & 1, qh = quad >> 1;
    int base[4][2];
#pragma unroll
    for (int sc = 0; sc < 4; sc++)
#pragma unroll
        for (int mt = 0; mt < 2; mt++) {
            int cell = mt * 16 + n;
            base[sc][mt] = ((a * 5 + cell / 5) * 24 + sc * 5 + cell % 5) * 3 + oct;
        }
    // tapoff24(t) = (t/5)*24 + t%5 for t = 0..25
    constexpr int TOFF24[26] = {0, 1, 2, 3, 4, 24, 25, 26, 27, 28, 48, 49, 50, 51,
                                52, 72, 73, 74, 75, 76, 96, 97, 98, 99, 100, 120};
    f32x4 acc[4][2][2];                  // [sc][mt][ntl]
#pragma unroll
    for (int sc = 0; sc < 4; sc++)
#pragma unroll
        for (int mt = 0; mt < 2; mt++)
#pragma unroll
            for (int ntl = 0; ntl < 2; ntl++) acc[sc][mt][ntl] = (f32x4){0.f, 0.f, 0.f, 0.f};
#pragma unroll
    for (int s = 0; s < 13; s++) {
        int toff3 = 3 * (qh ? TOFF24[2 * s + 1] : TOFF24[2 * s]);
        bf16x8 ah[4][2];
#pragma unroll
        for (int sc = 0; sc < 4; sc++)
#pragma unroll
            for (int mt = 0; mt < 2; mt++) ah[sc][mt] = xh8[base[sc][mt] + toff3];
#pragma unroll
        for (int ntl = 0; ntl < 2; ntl++) {
            bf16x8 bh = wh8[(s * 4 + bq * 2 + ntl) * 64 + lane];
#pragma unroll
            for (int sc = 0; sc < 4; sc++)
#pragma unroll
                for (int mt = 0; mt < 2; mt++)
                    acc[sc][mt][ntl] = __builtin_amdgcn_mfma_f32_16x16x32_bf16(ah[sc][mt], bh, acc[sc][mt][ntl], 0, 0, 0);
        }
    }
#pragma unroll
    for (int sc = 0; sc < 4; sc++) {
        int gsite = (bpr * 2 + a) * S2 + bpc * 4 + sc;
#pragma unroll
        for (int ntl = 0; ntl < 2; ntl++) {
            float m = NEGF;
#pragma unroll
            for (int mt = 0; mt < 2; mt++) {
#pragma unroll
                for (int r = 0; r < 4; r++) {
                    int cell = mt * 16 + quad * 4 + r;
                    if (cell < 25 && (mb[sc] & (1u << cell))) m = fmaxf(m, acc[sc][mt][ntl][r]);
                }
            }
            m = fmaxf(m, __shfl_xor(m, 16, 64));
            m = fmaxf(m, __shfl_xor(m, 32, 64));
            if (quad == 0) {
                int nt = bq * 2 + ntl;
                y2h[(size_t)gsite * 64 + nt * 16 + n] = mb[sc] ? f2bf(eluf(m)) : (unsigned short)0;
            }
        }
        if (bq == 0 && lane == 0) m2[gsite] = mb[sc] ? 1 : 0;
    }
}

// ---- layer 3: MFMA conv 5x5 64->128 + ELU + maxpool4 -> 36^2 ----------------
// LDS cell stride 9 uint4: 2-way bank conflicts.
__global__ __launch_bounds__(256) void k_l3(const unsigned short* __restrict__ y2h,
                                            const unsigned char* __restrict__ m2,
                                            const unsigned short* __restrict__ w3h,
                                            float* __restrict__ y3,
                                            unsigned char* __restrict__ m3) {
    __shared__ uint4 win_h4[144 * 9];    // 20736 B
    __shared__ unsigned char sm[64];
    int b = blockIdx.x;                  // 0..323
    int pr2 = b / 18, pc2 = b % 18;
    int r0 = pr2 * 8 - 2, c0 = pc2 * 8 - 2;
    int tid = threadIdx.x;
    for (int k = tid; k < 1152; k += 256) {
        int cellk = k >> 3, q = k & 7;
        int gr = r0 + cellk / 12, gc = c0 + cellk % 12;
        uint4 vh = make_uint4(0, 0, 0, 0);
        if (gr >= 0 && gr < S2 && gc >= 0 && gc < S2)
            vh = ((const uint4*)y2h)[(size_t)(gr * S2 + gc) * 8 + q];
        win_h4[cellk * 9 + q] = vh;
    }
    if (tid < 64) sm[tid] = m2[(pr2 * 8 + (tid >> 3)) * S2 + pc2 * 8 + (tid & 7)];
    __syncthreads();
    const bf16x8* winh8 = (const bf16x8*)win_h4;
    const bf16x8* w3h8 = (const bf16x8*)w3h;
    int wv = tid >> 6, lane = tid & 63;
    int quad = lane >> 4, n = lane & 15;
    int cellr = n >> 2, cellc = n & 3;
    f32x4 acc[4][2];                     // [si][ntl]
#pragma unroll
    for (int si = 0; si < 4; si++)
#pragma unroll
        for (int ntl = 0; ntl < 2; ntl++) acc[si][ntl] = (f32x4){0.f, 0.f, 0.f, 0.f};
    int bb = (wv * 2) * 64 + lane;       // s = 0
    bf16x8 bh0 = w3h8[bb];
    bf16x8 bh1 = w3h8[bb + 64];
#pragma unroll 2
    for (int s = 0; s < 50; s++) {
        int sp = s + 1 < 50 ? s + 1 : 0;
        int nb = (sp * 8 + wv * 2) * 64 + lane;
        bf16x8 nh0 = w3h8[nb];
        bf16x8 nh1 = w3h8[nb + 64];
        int t5 = s >> 1, cib = s & 1;
        int ky = t5 / 5, kx = t5 % 5;
        int common = ((cellr + ky) * 12 + (cellc + kx)) * 9 + cib * 4 + quad;
#pragma unroll
        for (int si = 0; si < 4; si++) {
            bf16x8 ah = winh8[common + (si >> 1) * 432 + (si & 1) * 36];
            acc[si][0] = __builtin_amdgcn_mfma_f32_16x16x32_bf16(ah, bh0, acc[si][0], 0, 0, 0);
            acc[si][1] = __builtin_amdgcn_mfma_f32_16x16x32_bf16(ah, bh1, acc[si][1], 0, 0, 0);
        }
        bh0 = nh0; bh1 = nh1;
    }
#pragma unroll
    for (int si = 0; si < 4; si++) {
        int srb = (si >> 1) * 4, scb = (si & 1) * 4;
        bool anyv = false;
#pragma unroll
        for (int i = 0; i < 16; i++) anyv |= (sm[(srb + (i >> 2)) * 8 + scb + (i & 3)] != 0);
        int sg = (2 * pr2 + (si >> 1)) * S3 + 2 * pc2 + (si & 1);
#pragma unroll
        for (int ntl = 0; ntl < 2; ntl++) {
            float mv = NEGF;
#pragma unroll
            for (int r = 0; r < 4; r++) {
                int cell = quad * 4 + r;
                if (sm[(srb + (cell >> 2)) * 8 + scb + (cell & 3)]) mv = fmaxf(mv, acc[si][ntl][r]);
            }
            mv = fmaxf(mv, __shfl_xor(mv, 16, 64));
            mv = fmaxf(mv, __shfl_xor(mv, 32, 64));
            if (quad == 0)
                y3[(size_t)sg * 128 + (wv * 2 + ntl) * 16 + n] = anyv ? eluf(mv) : 0.f;
        }
        if (tid == 0) m3[sg] = anyv ? 1 : 0;
    }
}

// ---- layer 4: MFMA conv 5x5 128->256 + ELU + maxpool4 -> 9^2 (fused) --------
// LDS: row stride 140, cell stride 17 (16B units): 2-way conflicts.
__global__ __launch_bounds__(1024) void k_l4(const float* __restrict__ y3,
                                             const unsigned char* __restrict__ m3,
                                             const unsigned short* __restrict__ w4h,
                                             float* __restrict__ y4) {
    __shared__ unsigned short winh[1120 * 8];   // 1120 x 16B = 17.92 KB
    __shared__ unsigned char sm[16];
    int p = blockIdx.x;                  // 0..80
    int ppr = p / S4, ppc = p % S4;
    int r0 = ppr * 4 - 2, c0 = ppc * 4 - 2;
    int tid = threadIdx.x;
    for (int k = tid; k < 2048; k += 1024) {    // k = cell*32 + q (uint2 units)
        int cellk = k >> 5, q = k & 31;
        int cr = cellk >> 3, cc = cellk & 7;
        int gr = r0 + cr, gc = c0 + cc;
        float4 v = make_float4(0.f, 0.f, 0.f, 0.f);
        if (gr >= 0 && gr < S3 && gc >= 0 && gc < S3)
            v = ((const float4*)y3)[((size_t)gr * S3 + gc) * 32 + q];
        unsigned short h0 = f2bf(v.x), h1 = f2bf(v.y), h2 = f2bf(v.z), h3 = f2bf(v.w);
        unsigned uh0 = (unsigned)h0 | ((unsigned)h1 << 16);
        unsigned uh1 = (unsigned)h2 | ((unsigned)h3 << 16);
        ((uint2*)winh)[cr * 280 + cc * 34 + q] = make_uint2(uh0, uh1);
    }
    if (tid < 16) sm[tid] = m3[(ppr * 4 + (tid >> 2)) * S3 + ppc * 4 + (tid & 3)];
    __syncthreads();
    const bf16x8* winh8 = (const bf16x8*)winh;
    const bf16x8* w4h8 = (const bf16x8*)w4h;
    int wv = tid >> 6, lane = tid & 63;   // wv = N-tile 0..15
    int quad = lane >> 4, n = lane & 15;
    int cellr = n >> 2, cellc = n & 3;
    f32x4 acc = {0.f, 0.f, 0.f, 0.f};
    int wb = wv * 64 + lane;             // frag(s, wv) = s*1024 + wb
    bf16x8 bha = w4h8[wb];               // s = 0
    bf16x8 bhb = w4h8[1024 + wb];        // s = 1
#pragma unroll 2
    for (int s = 0; s < 100; s++) {
        int sp = s + 2 < 100 ? s + 2 : 0;
        bf16x8 nh = w4h8[sp * 1024 + wb];
        int t5 = s >> 2, cib = s & 3;
        int ky = t5 / 5, kx = t5 % 5;
        int aidx = (cellr + ky) * 140 + (cellc + kx) * 17 + cib * 4 + quad;
        bf16x8 ah = winh8[aidx];
        acc = __builtin_amdgcn_mfma_f32_16x16x32_bf16(ah, bha, acc, 0, 0, 0);
        bha = bhb; bhb = nh;
    }
    bool anyv = false;
#pragma unroll
    for (int i = 0; i < 16; i++) anyv |= (sm[i] != 0);
    float m = NEGF;
#pragma unroll
    for (int r = 0; r < 4; r++) {
        int cell = quad * 4 + r;
        if (sm[cell]) m = fmaxf(m, acc[r]);
    }
    m = fmaxf(m, __shfl_xor(m, 16, 64));
    m = fmaxf(m, __shfl_xor(m, 32, 64));
    if (quad == 0)
        y4[(size_t)p * 256 + wv * 16 + n] = anyv ? eluf(m) : 0.f;
}

// ---- fc1 + fc2 + softmax (last-block epilogue via completion counter) -------
__global__ __launch_bounds__(256) void k_fc(const float* __restrict__ y4,
                                            const float* __restrict__ fc1_w,
                                            const float* __restrict__ fc1_b,
                                            const float* __restrict__ fc2_w,
                                            const float* __restrict__ fc2_b,
                                            float* __restrict__ h1,
                                            unsigned* __restrict__ cnt,
                                            float* __restrict__ out) {
    __shared__ float wsum[4][32];
    __shared__ int lastflag;
    __shared__ float hv[32];
    __shared__ float lg[5];
    int t = threadIdx.x;
    int i = blockIdx.x * 256 + t;
    int c = i / 81, rem = i % 81;
    float x = y4[(size_t)rem * 256 + c];
    const float4* wr = (const float4*)&fc1_w[(size_t)i * 32];
    float4 w[8];
#pragma unroll
    for (int q = 0; q < 8; q++) w[q] = wr[q];
    int lane = t & 63, wv = t >> 6;
#pragma unroll
    for (int q = 0; q < 8; q++) {
#pragma unroll
        for (int k = 0; k < 4; k++) {
            float v = x * ((&w[q].x)[k]);
            v += __shfl_down(v, 32, 64);
            v += __shfl_down(v, 16, 64);
            v += __shfl_down(v, 8, 64);
            v += __shfl_down(v, 4, 64);
            v += __shfl_down(v, 2, 64);
            v += __shfl_down(v, 1, 64);
            if (lane == 0) wsum[wv][q * 4 + k] = v;
        }
    }
    __syncthreads();
    if (t < 32) {
        float s = wsum[0][t] + wsum[1][t] + wsum[2][t] + wsum[3][t];
        atomicAdd(&h1[t], s);
    }
    __threadfence();                     // make this block's adds visible
    __syncthreads();
    if (t == 0) lastflag = (atomicAdd(cnt, 1u) == 80u) ? 1 : 0;
    __syncthreads();
    if (!lastflag) return;
    // last block: fc2 + softmax. h1 read via device-scope atomic loads.
    if (t < 32) hv[t] = eluf(atomicAdd(&h1[t], 0.f) + fc1_b[t]);
    __syncthreads();
    if (t < 5) {
        float s = fc2_b[t];
        for (int j = 0; j < 32; j++) s = fmaf(hv[j], fc2_w[j * 5 + t], s);
        lg[t] = s;
    }
    __syncthreads();
    if (t == 0) {
        float m = lg[0];
        for (int k = 1; k < 5; k++) m = fmaxf(m, lg[k]);
        float e[5], sum = 0.f;
        for (int k = 0; k < 5; k++) { e[k] = expf(lg[k] - m); sum += e[k]; }
        for (int k = 0; k < 5; k++) out[k] = e[k] / sum;
    }
}

extern "C" void kernel_launch(void* const* d_in, const int* in_sizes, int n_in,
                              void* d_out, int out_size, void* d_ws, size_t ws_size,
                              hipStream_t stream) {
    const int* coords = (const int*)d_in[0];
    const float* feats = (const float*)d_in[1];
    const float* w1 = (const float*)d_in[2];
    const float* w2 = (const float*)d_in[3];
    const float* w3 = (const float*)d_in[4];
    const float* w4 = (const float*)d_in[5];
    const float* fc1w = (const float*)d_in[6];
    const float* fc1b = (const float*)d_in[7];
    const float* fc2w = (const float*)d_in[8];
    const float* fc2b = (const float*)d_in[9];
    float* out = (float*)d_out;
    char* ws = (char*)d_ws;
    float* x0 = (float*)(ws + OFF_X0);
    unsigned* m0b = (unsigned*)(ws + OFF_M0B);
    unsigned short* y1h = (unsigned short*)(ws + OFF_Y1H);
    unsigned char* m1g = (unsigned char*)(ws + OFF_M1);
    unsigned char* m2g = (unsigned char*)(ws + OFF_M2);
    float* y3 = (float*)(ws + OFF_Y3);
    unsigned char* m3g = (unsigned char*)(ws + OFF_M3);
    float* y4 = (float*)(ws + OFF_Y4);
    float* h1 = (float*)(ws + OFF_H1);
    unsigned* cnt = (unsigned*)(ws + OFF_CNT);
    unsigned short* y2h = (unsigned short*)(ws + OFF_Y2H);
    unsigned short* w2h = (unsigned short*)(ws + OFF_W2H);
    unsigned short* w3h = (unsigned short*)(ws + OFF_W3H);
    unsigned short* w4h = (unsigned short*)(ws + OFF_W4H);
    int P = in_sizes[1];

    // one memset covers m0b bitfield + h1 accumulator + completion counter
    hipMemsetAsync(ws + OFF_M0B, 0, 1620000 + 160, stream);
    k_zero<<<(P + 255) / 256, 256, 0, stream>>>(coords, x0, P);
    k_scatter<<<(P + 255) / 256, 256, 0, stream>>>(coords, feats, x0, m0b, P);
    k_l1c<<<2025 + 513, 256, 0, stream>>>(x0, m0b, w1, w2, w3, w4,
                                          y1h, m1g, w2h, w3h, w4h);
    k_l2<<<72 * 36, 256, 0, stream>>>(y1h, m1g, w2h, y2h, m2g);
    k_l3<<<18 * 18, 256, 0, stream>>>(y2h, m2g, w3h, y3, m3g);
    k_l4<<<S4 * S4, 1024, 0, stream>>>(y3, m3g, w4h, y4);
    k_fc<<<81, 256, 0, stream>>>(y4, fc1w, fc1b, fc2w, fc2b, h1, cnt, out);
}

// Round 11
// 226.975 us; speedup vs baseline: 1.0567x; 1.0567x over previous
//
#include <hip/hip_runtime.h>
#include <math.h>

#define S0 3600
#define S1 720
#define S2 144
#define S3 36
#define S4 9
#define NEGF (-1e30f)

// ---- workspace layout (bytes). ws is 256 MiB (harness fill = 262144 KB).
static constexpr size_t OFF_X0  = 0;                                    // f32 [3600*3600] = 51,840,000
static constexpr size_t OFF_M0B = (size_t)S0 * S0 * 4;                  // u32 bitfield    = 1,620,000
static constexpr size_t OFF_H1  = OFF_M0B + 1620000;                    // f32 [32]
static constexpr size_t OFF_CNT = OFF_H1 + 128;                         // u32 completion counter
static constexpr size_t OFF_Y1H = OFF_CNT + 32;                         // bf16 [720*720*16] = 16,588,800
static constexpr size_t OFF_M1  = OFF_Y1H + (size_t)S1 * S1 * 16 * 2;   // u8  [720*720]
// aliased into dead x0 region (written only AFTER k_l1 part completes):
static constexpr size_t OFF_M2  = 1330000;                              // u8  [144*144]
static constexpr size_t OFF_Y3  = OFF_M2 + 20736;                       // f32 [36*36*128]
static constexpr size_t OFF_M3  = OFF_Y3 + (size_t)S3 * S3 * 128 * 4;   // u8  [36*36]
static constexpr size_t OFF_Y4  = OFF_M3 + 1296;                        // f32 [9*9*256]
// high region (beyond 80 MB): no aliasing with x0 -> converter can run with k_l1
static constexpr size_t OFF_Y2H = 80000000;                             // bf16 [20736*64] = 2,654,208
static constexpr size_t OFF_W2H = 84000000;                             // bf16 frags = 53,248
static constexpr size_t OFF_W3H = 84200000;                             // bf16 frags = 409,600
static constexpr size_t OFF_W4H = 84700000;                             // bf16 frags = 1,638,400 (ends 86.3 MB)

typedef __attribute__((ext_vector_type(8))) short bf16x8;
typedef __attribute__((ext_vector_type(4))) float f32x4;

__device__ __forceinline__ float eluf(float x) { return x > 0.f ? x : expm1f(x); }
__device__ __forceinline__ unsigned short f2bf(float f) {
    unsigned u = __float_as_uint(f);
    unsigned r = u + 0x7FFFu + ((u >> 16) & 1u);
    return (unsigned short)(r >> 16);
}
__device__ __forceinline__ float bf2f(unsigned short h) {
    return __uint_as_float((unsigned)h << 16);
}

// ---- zero x0 at the active coordinates --------------------------------------
__global__ __launch_bounds__(256) void k_zero(const int* __restrict__ coords,
                                              float* __restrict__ x0, int P) {
    int i = blockIdx.x * 256 + threadIdx.x;
    if (i >= P) return;
    x0[coords[2 * i] * S0 + coords[2 * i + 1]] = 0.f;
}

// ---- scatter points onto dense grid -----------------------------------------
__global__ __launch_bounds__(256) void k_scatter(const int* __restrict__ coords,
                                                 const float* __restrict__ feats,
                                                 float* __restrict__ x0,
                                                 unsigned* __restrict__ m0b, int P) {
    int i = blockIdx.x * 256 + threadIdx.x;
    if (i >= P) return;
    int r = coords[2 * i], c = coords[2 * i + 1];
    int idx = r * S0 + c;
    atomicAdd(&x0[idx], feats[i]);
    atomicOr(&m0b[idx >> 5], 1u << (idx & 31));
}

// ---- layer 1 (blocks 0..2024) + weight converter (blocks 2025..2537) --------
// l1: sparse conv 5x5 1->10 + ELU + maxpool5, bf16 output padded to 16 ch.
// Inactive sites write ONLY m1=0 (y1h left stale; k_l2 stages zeros via m1).
// cvtw: w2/w3/w4 -> MFMA B-fragment bf16 (independent; overlaps l1).
__global__ __launch_bounds__(256) void k_l1c(const float* __restrict__ x0,
                                             const unsigned* __restrict__ m0b,
                                             const float* __restrict__ w1,
                                             const float* __restrict__ w2,
                                             const float* __restrict__ w3,
                                             const float* __restrict__ w4,
                                             unsigned short* __restrict__ y1h,
                                             unsigned char* __restrict__ m1,
                                             unsigned short* __restrict__ w2h,
                                             unsigned short* __restrict__ w3h,
                                             unsigned short* __restrict__ w4h) {
    int b = blockIdx.x;
    int tid = threadIdx.x;
    if (b >= 2025) {                     // ---- converter branch ----
        int blk = b - 2025;
        if (blk < 13) {
            int t = blk * 256 + tid;
            int s = t >> 8, rem = t & 255;
            int nt = rem >> 6, lane = rem & 63;
            int quad = lane >> 4, n = lane & 15;
            int tap = 2 * s + (quad >> 1);
#pragma unroll
            for (int j = 0; j < 8; j++) {
                int ci = (quad & 1) * 8 + j;
                float v = 0.f;
                if (tap < 25 && ci < 10) v = w2[(tap * 10 + ci) * 64 + nt * 16 + n];
                w2h[(size_t)t * 8 + j] = f2bf(v);
            }
        } else if (blk < 113) {
            int t = (blk - 13) * 256 + tid;
            int s = t >> 9, rem = t & 511;
            int nt = rem >> 6, lane = rem & 63;
            int quad = lane >> 4, n = lane & 15;
            int t5 = s >> 1, cib = s & 1;
#pragma unroll
            for (int j = 0; j < 8; j++) {
                int ci = cib * 32 + quad * 8 + j;
                float v = w3[(size_t)(t5 * 64 + ci) * 128 + nt * 16 + n];
                w3h[(size_t)t * 8 + j] = f2bf(v);
            }
        } else {
            int t = (blk - 113) * 256 + tid;
            int s = t >> 10, rem = t & 1023;
            int nt = rem >> 6, lane = rem & 63;
            int quad = lane >> 4, n = lane & 15;
            int t5 = s >> 2, cib = s & 3;
#pragma unroll
            for (int j = 0; j < 8; j++) {
                int ci = cib * 32 + quad * 8 + j;
                float v = w4[(size_t)(t5 * 128 + ci) * 256 + nt * 16 + n];
                w4h[(size_t)t * 8 + j] = f2bf(v);
            }
        }
        return;
    }
    // ---- l1 branch ----
    __shared__ float w1s[250];
    if (tid < 250) w1s[tid] = w1[tid];
    __syncthreads();
    int t = b * 256 + tid;                // 0..720*720-1
    int pr = t / S1, pc = t % S1;
    int r0 = pr * 5 - 2, c0 = pc * 5 - 2;
    unsigned rows[9];
#pragma unroll
    for (int rr = 0; rr < 9; rr++) {
        unsigned bits = 0;
        int gr = r0 + rr;
        if (gr >= 0 && gr < S0) {
            int cs = c0 < 0 ? 0 : c0;
            int ce = c0 + 8 > S0 - 1 ? S0 - 1 : c0 + 8;
            int span = ce - cs;
            size_t i0 = (size_t)gr * S0 + cs;
            unsigned sh = (unsigned)(i0 & 31);
            unsigned long long two = (unsigned long long)m0b[i0 >> 5] >> sh;
            if ((int)sh + span >= 32)
                two |= (unsigned long long)m0b[(i0 >> 5) + 1] << (32 - sh);
            bits = (unsigned)(two & ((1u << (span + 1)) - 1));
            bits <<= (cs - c0);
        }
        rows[rr] = bits;
    }
    unsigned any25 = 0;
#pragma unroll
    for (int dy = 0; dy < 5; dy++) any25 |= (rows[2 + dy] >> 2) & 0x1Fu;
    if (!any25) {
        m1[t] = 0;
        return;
    }
    float2 mx[5];
#pragma unroll
    for (int q = 0; q < 5; q++) mx[q] = make_float2(NEGF, NEGF);
    for (int dy = 0; dy < 5; dy++) {
        unsigned crow = (rows[2 + dy] >> 2) & 0x1Fu;
        while (crow) {
            int dx = __ffs(crow) - 1; crow &= crow - 1;
            float2 acc[5];
#pragma unroll
            for (int q = 0; q < 5; q++) acc[q] = make_float2(0.f, 0.f);
#pragma unroll
            for (int ky = 0; ky < 5; ky++) {
                unsigned nrow = (rows[dy + ky] >> dx) & 0x1Fu;
                size_t rowbase = (size_t)(r0 + dy + ky) * S0 + (c0 + dx);
                while (nrow) {
                    int kx = __ffs(nrow) - 1; nrow &= nrow - 1;
                    float xv = x0[rowbase + kx];
                    const float2* wp = (const float2*)&w1s[(ky * 5 + kx) * 10];
#pragma unroll
                    for (int q = 0; q < 5; q++) {
                        float2 w = wp[q];
                        acc[q].x = fmaf(xv, w.x, acc[q].x);
                        acc[q].y = fmaf(xv, w.y, acc[q].y);
                    }
                }
            }
#pragma unroll
            for (int q = 0; q < 5; q++) {
                mx[q].x = fmaxf(mx[q].x, acc[q].x);
                mx[q].y = fmaxf(mx[q].y, acc[q].y);
            }
        }
    }
    unsigned u[8];
#pragma unroll
    for (int q = 0; q < 5; q++) {
        unsigned short h0 = f2bf(eluf(mx[q].x));
        unsigned short h1 = f2bf(eluf(mx[q].y));
        u[q] = (unsigned)h0 | ((unsigned)h1 << 16);
    }
    u[5] = 0; u[6] = 0; u[7] = 0;
    uint4* yo = (uint4*)&y1h[(size_t)t * 16];
    yo[0] = make_uint4(u[0], u[1], u[2], u[3]);
    yo[1] = make_uint4(u[4], u[5], u[6], u[7]);
    m1[t] = 1;
}

// ---- layer 2: MFMA conv 5x5 10->64 + ELU + maxpool5 -> 144^2 ----------------
// Round-9 geometry (measured best): block = 2x2 sites, 5184 blocks, 14x14
// halo, 48 B/cell LDS stride, 4 blocks/CU. Staging gated on m1 (y1h is
// stale at inactive sites). Wave (a = site-row, bq = nt-pair).
__global__ __launch_bounds__(256, 4) void k_l2(const unsigned short* __restrict__ y1h,
                                               const unsigned char* __restrict__ m1,
                                               const unsigned short* __restrict__ w2h,
                                               unsigned short* __restrict__ y2h,
                                               unsigned char* __restrict__ m2) {
    __shared__ unsigned short winh[240 * 24];   // 11.52 KB, 48 B/cell
    __shared__ unsigned char sm[196];
    int b = blockIdx.x;                  // 0..5183
    int bpr = b / 72, bpc = b % 72;
    int r0 = bpr * 10 - 2, c0 = bpc * 10 - 2;
    int tid = threadIdx.x;
    if (tid < 240) {
        uint4 v0 = make_uint4(0, 0, 0, 0), v1 = v0;
        unsigned char msk = 0;
        if (tid < 196) {
            int gr = r0 + tid / 14, gc = c0 + tid % 14;
            bool ok = (gr >= 0 && gr < S1 && gc >= 0 && gc < S1);
            msk = ok ? m1[gr * S1 + gc] : (unsigned char)0;
            sm[tid] = msk;
            if (msk) {
                const uint4* src = (const uint4*)&y1h[(size_t)(gr * S1 + gc) * 16];
                v0 = src[0];
                v1 = src[1];
            }
        }
        uint4* dh = (uint4*)&winh[tid * 24];
        dh[0] = v0;
        dh[1] = v1;
    }
    __syncthreads();
    int wv = tid >> 6;
    int a = wv >> 1, bq = wv & 1;        // a = site row (sr), bq = nt-pair
    int lane = tid & 63, quad = lane >> 4, n = lane & 15;
    // mbits via ballot: lanes 0..24 -> site (a,0), lanes 32..56 -> site (a,1)
    int cql = lane & 31, s01l = lane >> 5;
    bool pv = false;
    if (cql < 25)
        pv = sm[(a * 5 + 2 + cql / 5) * 14 + s01l * 5 + 2 + cql % 5] != 0;
    unsigned long long bal = __ballot(pv);
    unsigned mb[2];
    mb[0] = (unsigned)(bal & 0x1FFFFFFull);
    mb[1] = (unsigned)((bal >> 32) & 0x1FFFFFFull);
    const bf16x8* wh8 = (const bf16x8*)w2h;
    const bf16x8* xh8 = (const bf16x8*)winh;
    int oct = quad & 1, qh = quad >> 1;
    int base[2][2];
#pragma unroll
    for (int s01 = 0; s01 < 2; s01++)
#pragma unroll
        for (int mt = 0; mt < 2; mt++) {
            int cell = mt * 16 + n;
            base[s01][mt] = ((a * 5 + cell / 5) * 14 + s01 * 5 + cell % 5) * 3 + oct;
        }
    // tapoff(t) = (t/5)*14 + t%5 for t = 0..25
    constexpr int TOFF[26] = {0, 1, 2, 3, 4, 14, 15, 16, 17, 18, 28, 29, 30, 31,
                              32, 42, 43, 44, 45, 46, 56, 57, 58, 59, 60, 70};
    f32x4 acc[2][2][2];                  // [s01][mt][ntl]
#pragma unroll
    for (int s01 = 0; s01 < 2; s01++)
#pragma unroll
        for (int mt = 0; mt < 2; mt++)
#pragma unroll
            for (int ntl = 0; ntl < 2; ntl++) acc[s01][mt][ntl] = (f32x4){0.f, 0.f, 0.f, 0.f};
#pragma unroll
    for (int s = 0; s < 13; s++) {
        int toff3 = 3 * (qh ? TOFF[2 * s + 1] : TOFF[2 * s]);
        bf16x8 ah[2][2];
#pragma unroll
        for (int s01 = 0; s01 < 2; s01++)
#pragma unroll
            for (int mt = 0; mt < 2; mt++) ah[s01][mt] = xh8[base[s01][mt] + toff3];
#pragma unroll
        for (int ntl = 0; ntl < 2; ntl++) {
            bf16x8 bh = wh8[(s * 4 + bq * 2 + ntl) * 64 + lane];
#pragma unroll
            for (int s01 = 0; s01 < 2; s01++)
#pragma unroll
                for (int mt = 0; mt < 2; mt++)
                    acc[s01][mt][ntl] = __builtin_amdgcn_mfma_f32_16x16x32_bf16(ah[s01][mt], bh, acc[s01][mt][ntl], 0, 0, 0);
        }
    }
#pragma unroll
    for (int s01 = 0; s01 < 2; s01++) {
        int gsite = (bpr * 2 + a) * S2 + bpc * 2 + s01;
#pragma unroll
        for (int ntl = 0; ntl < 2; ntl++) {
            float m = NEGF;
#pragma unroll
            for (int mt = 0; mt < 2; mt++) {
#pragma unroll
                for (int r = 0; r < 4; r++) {
                    int cell = mt * 16 + quad * 4 + r;
                    if (cell < 25 && (mb[s01] & (1u << cell))) m = fmaxf(m, acc[s01][mt][ntl][r]);
                }
            }
            m = fmaxf(m, __shfl_xor(m, 16, 64));
            m = fmaxf(m, __shfl_xor(m, 32, 64));
            if (quad == 0) {
                int nt = bq * 2 + ntl;
                y2h[(size_t)gsite * 64 + nt * 16 + n] = mb[s01] ? f2bf(eluf(m)) : (unsigned short)0;
            }
        }
        if (bq == 0 && lane == 0) m2[gsite] = mb[s01] ? 1 : 0;
    }
}

// ---- layer 3: MFMA conv 5x5 64->128 + ELU + maxpool4 -> 36^2 ----------------
// LDS cell stride 9 uint4: 2-way bank conflicts.
__global__ __launch_bounds__(256) void k_l3(const unsigned short* __restrict__ y2h,
                                            const unsigned char* __restrict__ m2,
                                            const unsigned short* __restrict__ w3h,
                                            float* __restrict__ y3,
                                            unsigned char* __restrict__ m3) {
    __shared__ uint4 win_h4[144 * 9];    // 20736 B
    __shared__ unsigned char sm[64];
    int b = blockIdx.x;                  // 0..323
    int pr2 = b / 18, pc2 = b % 18;
    int r0 = pr2 * 8 - 2, c0 = pc2 * 8 - 2;
    int tid = threadIdx.x;
    for (int k = tid; k < 1152; k += 256) {
        int cellk = k >> 3, q = k & 7;
        int gr = r0 + cellk / 12, gc = c0 + cellk % 12;
        uint4 vh = make_uint4(0, 0, 0, 0);
        if (gr >= 0 && gr < S2 && gc >= 0 && gc < S2)
            vh = ((const uint4*)y2h)[(size_t)(gr * S2 + gc) * 8 + q];
        win_h4[cellk * 9 + q] = vh;
    }
    if (tid < 64) sm[tid] = m2[(pr2 * 8 + (tid >> 3)) * S2 + pc2 * 8 + (tid & 7)];
    __syncthreads();
    const bf16x8* winh8 = (const bf16x8*)win_h4;
    const bf16x8* w3h8 = (const bf16x8*)w3h;
    int wv = tid >> 6, lane = tid & 63;
    int quad = lane >> 4, n = lane & 15;
    int cellr = n >> 2, cellc = n & 3;
    f32x4 acc[4][2];                     // [si][ntl]
#pragma unroll
    for (int si = 0; si < 4; si++)
#pragma unroll
        for (int ntl = 0; ntl < 2; ntl++) acc[si][ntl] = (f32x4){0.f, 0.f, 0.f, 0.f};
    int bb = (wv * 2) * 64 + lane;       // s = 0
    bf16x8 bh0 = w3h8[bb];
    bf16x8 bh1 = w3h8[bb + 64];
#pragma unroll 2
    for (int s = 0; s < 50; s++) {
        int sp = s + 1 < 50 ? s + 1 : 0;
        int nb = (sp * 8 + wv * 2) * 64 + lane;
        bf16x8 nh0 = w3h8[nb];
        bf16x8 nh1 = w3h8[nb + 64];
        int t5 = s >> 1, cib = s & 1;
        int ky = t5 / 5, kx = t5 % 5;
        int common = ((cellr + ky) * 12 + (cellc + kx)) * 9 + cib * 4 + quad;
#pragma unroll
        for (int si = 0; si < 4; si++) {
            bf16x8 ah = winh8[common + (si >> 1) * 432 + (si & 1) * 36];
            acc[si][0] = __builtin_amdgcn_mfma_f32_16x16x32_bf16(ah, bh0, acc[si][0], 0, 0, 0);
            acc[si][1] = __builtin_amdgcn_mfma_f32_16x16x32_bf16(ah, bh1, acc[si][1], 0, 0, 0);
        }
        bh0 = nh0; bh1 = nh1;
    }
#pragma unroll
    for (int si = 0; si < 4; si++) {
        int srb = (si >> 1) * 4, scb = (si & 1) * 4;
        bool anyv = false;
#pragma unroll
        for (int i = 0; i < 16; i++) anyv |= (sm[(srb + (i >> 2)) * 8 + scb + (i & 3)] != 0);
        int sg = (2 * pr2 + (si >> 1)) * S3 + 2 * pc2 + (si & 1);
#pragma unroll
        for (int ntl = 0; ntl < 2; ntl++) {
            float mv = NEGF;
#pragma unroll
            for (int r = 0; r < 4; r++) {
                int cell = quad * 4 + r;
                if (sm[(srb + (cell >> 2)) * 8 + scb + (cell & 3)]) mv = fmaxf(mv, acc[si][ntl][r]);
            }
            mv = fmaxf(mv, __shfl_xor(mv, 16, 64));
            mv = fmaxf(mv, __shfl_xor(mv, 32, 64));
            if (quad == 0)
                y3[(size_t)sg * 128 + (wv * 2 + ntl) * 16 + n] = anyv ? eluf(mv) : 0.f;
        }
        if (tid == 0) m3[sg] = anyv ? 1 : 0;
    }
}

// ---- layer 4: MFMA conv 5x5 128->256 + ELU + maxpool4 -> 9^2 (fused) --------
// LDS: row stride 140, cell stride 17 (16B units): 2-way conflicts.
__global__ __launch_bounds__(1024) void k_l4(const float* __restrict__ y3,
                                             const unsigned char* __restrict__ m3,
                                             const unsigned short* __restrict__ w4h,
                                             float* __restrict__ y4) {
    __shared__ unsigned short winh[1120 * 8];   // 1120 x 16B = 17.92 KB
    __shared__ unsigned char sm[16];
    int p = blockIdx.x;                  // 0..80
    int ppr = p / S4, ppc = p % S4;
    int r0 = ppr * 4 - 2, c0 = ppc * 4 - 2;
    int tid = threadIdx.x;
    for (int k = tid; k < 2048; k += 1024) {    // k = cell*32 + q (uint2 units)
        int cellk = k >> 5, q = k & 31;
        int cr = cellk >> 3, cc = cellk & 7;
        int gr = r0 + cr, gc = c0 + cc;
        float4 v = make_float4(0.f, 0.f, 0.f, 0.f);
        if (gr >= 0 && gr < S3 && gc >= 0 && gc < S3)
            v = ((const float4*)y3)[((size_t)gr * S3 + gc) * 32 + q];
        unsigned short h0 = f2bf(v.x), h1 = f2bf(v.y), h2 = f2bf(v.z), h3 = f2bf(v.w);
        unsigned uh0 = (unsigned)h0 | ((unsigned)h1 << 16);
        unsigned uh1 = (unsigned)h2 | ((unsigned)h3 << 16);
        ((uint2*)winh)[cr * 280 + cc * 34 + q] = make_uint2(uh0, uh1);
    }
    if (tid < 16) sm[tid] = m3[(ppr * 4 + (tid >> 2)) * S3 + ppc * 4 + (tid & 3)];
    __syncthreads();
    const bf16x8* winh8 = (const bf16x8*)winh;
    const bf16x8* w4h8 = (const bf16x8*)w4h;
    int wv = tid >> 6, lane = tid & 63;   // wv = N-tile 0..15
    int quad = lane >> 4, n = lane & 15;
    int cellr = n >> 2, cellc = n & 3;
    f32x4 acc = {0.f, 0.f, 0.f, 0.f};
    int wb = wv * 64 + lane;             // frag(s, wv) = s*1024 + wb
    bf16x8 bha = w4h8[wb];               // s = 0
    bf16x8 bhb = w4h8[1024 + wb];        // s = 1
#pragma unroll 2
    for (int s = 0; s < 100; s++) {
        int sp = s + 2 < 100 ? s + 2 : 0;
        bf16x8 nh = w4h8[sp * 1024 + wb];
        int t5 = s >> 2, cib = s & 3;
        int ky = t5 / 5, kx = t5 % 5;
        int aidx = (cellr + ky) * 140 + (cellc + kx) * 17 + cib * 4 + quad;
        bf16x8 ah = winh8[aidx];
        acc = __builtin_amdgcn_mfma_f32_16x16x32_bf16(ah, bha, acc, 0, 0, 0);
        bha = bhb; bhb = nh;
    }
    bool anyv = false;
#pragma unroll
    for (int i = 0; i < 16; i++) anyv |= (sm[i] != 0);
    float m = NEGF;
#pragma unroll
    for (int r = 0; r < 4; r++) {
        int cell = quad * 4 + r;
        if (sm[cell]) m = fmaxf(m, acc[r]);
    }
    m = fmaxf(m, __shfl_xor(m, 16, 64));
    m = fmaxf(m, __shfl_xor(m, 32, 64));
    if (quad == 0)
        y4[(size_t)p * 256 + wv * 16 + n] = anyv ? eluf(m) : 0.f;
}

// ---- fc1 + fc2 + softmax (last-block epilogue via completion counter) -------
__global__ __launch_bounds__(256) void k_fc(const float* __restrict__ y4,
                                            const float* __restrict__ fc1_w,
                                            const float* __restrict__ fc1_b,
                                            const float* __restrict__ fc2_w,
                                            const float* __restrict__ fc2_b,
                                            float* __restrict__ h1,
                                            unsigned* __restrict__ cnt,
                                            float* __restrict__ out) {
    __shared__ float wsum[4][32];
    __shared__ int lastflag;
    __shared__ float hv[32];
    __shared__ float lg[5];
    int t = threadIdx.x;
    int i = blockIdx.x * 256 + t;
    int c = i / 81, rem = i % 81;
    float x = y4[(size_t)rem * 256 + c];
    const float4* wr = (const float4*)&fc1_w[(size_t)i * 32];
    float4 w[8];
#pragma unroll
    for (int q = 0; q < 8; q++) w[q] = wr[q];
    int lane = t & 63, wv = t >> 6;
#pragma unroll
    for (int q = 0; q < 8; q++) {
#pragma unroll
        for (int k = 0; k < 4; k++) {
            float v = x * ((&w[q].x)[k]);
            v += __shfl_down(v, 32, 64);
            v += __shfl_down(v, 16, 64);
            v += __shfl_down(v, 8, 64);
            v += __shfl_down(v, 4, 64);
            v += __shfl_down(v, 2, 64);
            v += __shfl_down(v, 1, 64);
            if (lane == 0) wsum[wv][q * 4 + k] = v;
        }
    }
    __syncthreads();
    if (t < 32) {
        float s = wsum[0][t] + wsum[1][t] + wsum[2][t] + wsum[3][t];
        atomicAdd(&h1[t], s);
    }
    __threadfence();                     // make this block's adds visible
    __syncthreads();
    if (t == 0) lastflag = (atomicAdd(cnt, 1u) == 80u) ? 1 : 0;
    __syncthreads();
    if (!lastflag) return;
    // last block: fc2 + softmax. h1 read via device-scope atomic loads.
    if (t < 32) hv[t] = eluf(atomicAdd(&h1[t], 0.f) + fc1_b[t]);
    __syncthreads();
    if (t < 5) {
        float s = fc2_b[t];
        for (int j = 0; j < 32; j++) s = fmaf(hv[j], fc2_w[j * 5 + t], s);
        lg[t] = s;
    }
    __syncthreads();
    if (t == 0) {
        float m = lg[0];
        for (int k = 1; k < 5; k++) m = fmaxf(m, lg[k]);
        float e[5], sum = 0.f;
        for (int k = 0; k < 5; k++) { e[k] = expf(lg[k] - m); sum += e[k]; }
        for (int k = 0; k < 5; k++) out[k] = e[k] / sum;
    }
}

extern "C" void kernel_launch(void* const* d_in, const int* in_sizes, int n_in,
                              void* d_out, int out_size, void* d_ws, size_t ws_size,
                              hipStream_t stream) {
    const int* coords = (const int*)d_in[0];
    const float* feats = (const float*)d_in[1];
    const float* w1 = (const float*)d_in[2];
    const float* w2 = (const float*)d_in[3];
    const float* w3 = (const float*)d_in[4];
    const float* w4 = (const float*)d_in[5];
    const float* fc1w = (const float*)d_in[6];
    const float* fc1b = (const float*)d_in[7];
    const float* fc2w = (const float*)d_in[8];
    const float* fc2b = (const float*)d_in[9];
    float* out = (float*)d_out;
    char* ws = (char*)d_ws;
    float* x0 = (float*)(ws + OFF_X0);
    unsigned* m0b = (unsigned*)(ws + OFF_M0B);
    unsigned short* y1h = (unsigned short*)(ws + OFF_Y1H);
    unsigned char* m1g = (unsigned char*)(ws + OFF_M1);
    unsigned char* m2g = (unsigned char*)(ws + OFF_M2);
    float* y3 = (float*)(ws + OFF_Y3);
    unsigned char* m3g = (unsigned char*)(ws + OFF_M3);
    float* y4 = (float*)(ws + OFF_Y4);
    float* h1 = (float*)(ws + OFF_H1);
    unsigned* cnt = (unsigned*)(ws + OFF_CNT);
    unsigned short* y2h = (unsigned short*)(ws + OFF_Y2H);
    unsigned short* w2h = (unsigned short*)(ws + OFF_W2H);
    unsigned short* w3h = (unsigned short*)(ws + OFF_W3H);
    unsigned short* w4h = (unsigned short*)(ws + OFF_W4H);
    int P = in_sizes[1];

    // one memset covers m0b bitfield + h1 accumulator + completion counter
    hipMemsetAsync(ws + OFF_M0B, 0, 1620000 + 160, stream);
    k_zero<<<(P + 255) / 256, 256, 0, stream>>>(coords, x0, P);
    k_scatter<<<(P + 255) / 256, 256, 0, stream>>>(coords, feats, x0, m0b, P);
    k_l1c<<<2025 + 513, 256, 0, stream>>>(x0, m0b, w1, w2, w3, w4,
                                          y1h, m1g, w2h, w3h, w4h);
    k_l2<<<72 * 72, 256, 0, stream>>>(y1h, m1g, w2h, y2h, m2g);
    k_l3<<<18 * 18, 256, 0, stream>>>(y2h, m2g, w3h, y3, m3g);
    k_l4<<<S4 * S4, 1024, 0, stream>>>(y3, m3g, w4h, y4);
    k_fc<<<81, 256, 0, stream>>>(y4, fc1w, fc1b, fc2w, fc2b, h1, cnt, out);
}